// Round 5
// baseline (131.528 us; speedup 1.0000x reference)
//
#include <hip/hip_runtime.h>
#include <math.h>

#define BB   4
#define HH   96
#define WW   96
#define HW   (HH * WW)          // 9216
#define CIN  64
#define COUT 64
#define C2B  192                // bf16 row: fi[64] fj[64](permuted) flow[2] pad
                                // 384 B = 3 x 128-B lines; fj region 128-B aligned
#define NROW (BB * HW)          // 36864
#define ZROW NROW               // all-zero row
#define NSTRIP (NROW / 16)      // 2304 strips of 16 positions = fused grid
#define BPX3 (NSTRIP / 8)       // 288 fused blocks per XCD
#define NA   (9 * 5 * 2 * 512)  // wa2f elements (46080), fragment-dense
#define NW   (9 * 2 * 4 * 512)  // wb2f elements (36864), fragment-dense
#define PXB2 (NROW / 32)        // 1152 prep X-blocks (64 rows, half channels)
#define PWBLK 324               // weight blocks covering NA+NW elements
#define TSX  35                 // prep LDS tile stride (dwords), conflict-free
#define PR   55                 // patch row-dim (54 rows + 1 pad)

typedef short v8s __attribute__((ext_vector_type(8)));   // 8 bf16 = 4 VGPRs
typedef float v4f __attribute__((ext_vector_type(4)));

__device__ __forceinline__ unsigned short f2bf(float f) {
    unsigned u = __float_as_uint(f);
    return (unsigned short)((u + 0x7FFFu + ((u >> 16) & 1u)) >> 16);  // RTN-even
}
__device__ __forceinline__ unsigned pack2(float a, float b) {
    return (unsigned)f2bf(a) | ((unsigned)f2bf(b) << 16);
}
__device__ __forceinline__ unsigned bil2(unsigned a, unsigned b, unsigned c,
                                         unsigned d, float w00, float w01,
                                         float w10, float w11) {
    float lo = w00 * __uint_as_float(a << 16) + w01 * __uint_as_float(b << 16)
             + w10 * __uint_as_float(c << 16) + w11 * __uint_as_float(d << 16);
    float hi = w00 * __uint_as_float(a & 0xffff0000u)
             + w01 * __uint_as_float(b & 0xffff0000u)
             + w10 * __uint_as_float(c & 0xffff0000u)
             + w11 * __uint_as_float(d & 0xffff0000u);
    return pack2(lo, hi);
}

// ---------------------------------------------------------------------------
// Prep (unchanged, known-good). fj chunks stored PERMUTED within the row
// (orig chunk o -> physical (o&3)*2+(o>>2)) so a deform lane's two K-chunks
// are address-adjacent (+0/+16B). Conv reads remap at compile time.
// ---------------------------------------------------------------------------
__global__ __launch_bounds__(256) void prep_kernel(
    const float* __restrict__ fi, const float* __restrict__ fj,
    const float* __restrict__ fl, const float* __restrict__ w_off,
    const float* __restrict__ w_mod, const float* __restrict__ w_reg,
    unsigned short* __restrict__ xt, unsigned short* __restrict__ wa2f,
    unsigned short* __restrict__ wb2f)
{
    int blk = blockIdx.x;
    if (blk < PXB2) {
        __shared__ __align__(16) unsigned tile[64 * TSX];  // 9 KB
        int tid = threadIdx.x;
        int p = tid & 63, cg = tid >> 6;    // position, channel-group 0..3
        int u = blk >> 1, half = blk & 1;
        int r0 = u * 64;
        int b = r0 / HW;                    // 64-row strip never straddles b
        int hw = r0 - b * HW + p;
        uint4* dst = (uint4*)(xt + (size_t)r0 * C2B);      // 24 quads per row
        if (half == 0) {                    // fi -> chunks 0..7
            const float* pi = fi + (size_t)b * CIN * HW + hw;
#pragma unroll
            for (int d = 0; d < 8; ++d) {
                int c = cg * 16 + 2 * d;
                tile[p * TSX + cg * 8 + d] =
                    pack2(pi[(size_t)c * HW], pi[(size_t)(c + 1) * HW]);
            }
            __syncthreads();
#pragma unroll
            for (int i = 0; i < 2; ++i) {   // 512 quads: 8 per row
                int gq = i * 256 + tid;
                int rl = gq >> 3, c4 = gq & 7;
                const unsigned* s = &tile[rl * TSX + c4 * 4];
                uint4 v = {s[0], s[1], s[2], s[3]};
                dst[rl * 24 + c4] = v;
            }
        } else {                            // fj(permuted)+flow+pad -> 8..23
            const float* pj = fj + (size_t)b * CIN * HW + hw;
#pragma unroll
            for (int d = 0; d < 8; ++d) {
                int c = cg * 16 + 2 * d;
                tile[p * TSX + cg * 8 + d] =
                    pack2(pj[(size_t)c * HW], pj[(size_t)(c + 1) * HW]);
            }
            if (cg == 0) {
                const float* pf = fl + (size_t)b * 2 * HW + hw;
                tile[p * TSX + 32] = pack2(pf[0], pf[HW]);
            }
            __syncthreads();
#pragma unroll
            for (int i = 0; i < 4; ++i) {   // 1024 quads: 16 per row (8..23)
                int gq = i * 256 + tid;
                int rl = gq >> 4, c4 = gq & 15;
                uint4 v = {0u, 0u, 0u, 0u};
                if (c4 < 8) {
                    const unsigned* s = &tile[rl * TSX + c4 * 4];
                    v.x = s[0]; v.y = s[1]; v.z = s[2]; v.w = s[3];
                } else if (c4 == 8) {
                    v.x = tile[rl * TSX + 32];
                }
                int pc4 = (c4 < 8) ? ((c4 & 3) * 2 + (c4 >> 2)) : c4;  // permute
                dst[rl * 24 + 8 + pc4] = v;
            }
        }
    } else if (blk < PXB2 + PWBLK) {
        int e = (blk - PXB2) * 256 + threadIdx.x;
        if (e < NA) {                       // wa2f, fragment-dense
            int t  = e / 5120;
            int r1 = e - t * 5120;
            int ks = r1 >> 10;
            int r2 = r1 & 1023;
            int nt = r2 >> 9;
            int l9 = r2 & 511;
            int l  = l9 >> 3, ee = l9 & 7;
            int m  = l & 15, g = l >> 4;
            int oc = nt * 16 + m;
            int ch = ks * 32 + g * 8 + ee;
            float v = 0.0f;
            if (oc < 27 && ch < 130) {
                if (oc < 18) v = w_off[((size_t)oc * 130 + ch) * 9 + t];
                else         v = w_mod[((size_t)(oc - 18) * 130 + ch) * 9 + t];
            }
            wa2f[e] = f2bf(v);
        } else {
            int e2 = e - NA;
            if (e2 < NW) {                  // wb2f, fragment-dense
                int k  = e2 >> 12;
                int r1 = e2 & 4095;
                int ks = r1 >> 11;
                int r2 = r1 & 2047;
                int nt = r2 >> 9;
                int l9 = r2 & 511;
                int l  = l9 >> 3, ee = l9 & 7;
                int m  = l & 15, g = l >> 4;
                int o  = nt * 16 + m;
                int c  = ks * 32 + g * 8 + ee;
                wb2f[e2] = f2bf(w_reg[((size_t)o * 64 + c) * 9 + k]);
            }
        }
    } else {
        if (threadIdx.x < 24) {             // zero row, 24 dwordx4
            uint4 z = {0u, 0u, 0u, 0u};
            ((uint4*)(xt + (size_t)ZROW * C2B))[threadIdx.x] = z;
        }
    }
}

// ---------------------------------------------------------------------------
// Fused conv + deform. R19: R17 structure + FULL WEIGHT PRELOAD (ILP round).
//  Theory: every variant R15-R18 was stall-bound at low VGPR (compiler chose
//  40-64): weight-load->MFMA chains serialized in both phases. All B-frags
//  are position-independent -> load them at kernel ENTRY into registers
//  (latency hides under staging), pin with empty asm so they can't be
//  rematerialized. Phase 1 = ds_read->MFMA only; phase 2's only exposed
//  wait is the gather batch.
//  __launch_bounds__(512,2): <=256 VGPR, 1 block/CU. Deliberate trade:
//  occupancy 30-75% was proven worthless (R15-R18); registers proven
//  valuable (R16 regression at VGPR=40).
// ---------------------------------------------------------------------------
__global__ __launch_bounds__(512, 2) void fused_kernel(
    const unsigned short* __restrict__ xt,
    const unsigned short* __restrict__ wa2f,
    const unsigned short* __restrict__ wb2f,
    const float* __restrict__ b_off, const float* __restrict__ b_mod,
    float* __restrict__ out)
{
    // pool: [0,17600) patch4 (stage..barrier A) | [0,32768) red2 (after B)
    __shared__ __align__(16) unsigned char pool[32768];
    __shared__ __align__(16) float red1[8][8][64];    // 16 KB ph1 partials
    __shared__ float lraw[16 * 28];                   // 1.8 KB offsets/mods

    uint4* patch4 = (uint4*)pool;
    float* red2   = (float*)pool;                     // [8][16][64]

    int l = threadIdx.x & 63;
    int wid = __builtin_amdgcn_readfirstlane(threadIdx.x >> 6);  // 0..7
    int m = l & 15, g = l >> 4;
    int strip = (blockIdx.x & 7) * BPX3 + (blockIdx.x >> 3);  // XCD-contiguous
    int b = strip / (HW / 16);              // wave-uniform
    int hw0 = (strip - b * (HW / 16)) * 16;
    int hw = hw0 + m;
    int x = hw % WW, y = hw / WW;
    int y0b = hw0 / WW, x0b = hw0 - y0b * WW;   // strip base (x0b mult of 16)

    // ==== ENTRY PRELOADS: all weight fragments this wave will ever need ====
    int nu = (wid < 5) ? 6 : 5;             // ph1: 45 units over 8 waves
    v8s preA[6][2];
#pragma unroll
    for (int i = 0; i < 6; ++i) {
        if (i < nu) {
            int u = wid + 8 * i;            // unit = t*5+ks, wave-uniform
            const unsigned short* wp = wa2f + ((size_t)(u * 2)) * 512 + l * 8;
            preA[i][0] = *(const v8s*)(wp);
            preA[i][1] = *(const v8s*)(wp + 512);
            asm volatile("" : "+v"(preA[i][0]), "+v"(preA[i][1]));
        }
    }
    v8s preB[8];                            // ph2 weights, tap = wid
#pragma unroll
    for (int nt = 0; nt < 4; ++nt) {
        preB[nt * 2 + 0] = *(const v8s*)(wb2f
            + ((size_t)((wid * 2 + 0) * 4 + nt)) * 512 + l * 8);
        preB[nt * 2 + 1] = *(const v8s*)(wb2f
            + ((size_t)((wid * 2 + 1) * 4 + nt)) * 512 + l * 8);
        asm volatile("" : "+v"(preB[nt * 2 + 0]), "+v"(preB[nt * 2 + 1]));
    }
    v8s preB8[8];                           // wave 7 only: tap 8 weights
    if (wid == 7) {
#pragma unroll
        for (int nt = 0; nt < 4; ++nt) {
            preB8[nt * 2 + 0] = *(const v8s*)(wb2f
                + ((size_t)((8 * 2 + 0) * 4 + nt)) * 512 + l * 8);
            preB8[nt * 2 + 1] = *(const v8s*)(wb2f
                + ((size_t)((8 * 2 + 1) * 4 + nt)) * 512 + l * 8);
            asm volatile("" : "+v"(preB8[nt * 2 + 0]), "+v"(preB8[nt * 2 + 1]));
        }
    }

    // ---- Stage the 3x18-row patch (all 9 taps' A-data), dense loads ----
#pragma unroll
    for (int i = 0; i < 3; ++i) {
        int item = i * 512 + threadIdx.x;   // (run,row18,c8) row-major
        if (item < 1080) {
            int run = item / 360;
            int rem = item - run * 360;
            int r18 = rem / 20;
            int c8  = rem - r18 * 20;
            int yy = y0b + run - 1;
            int xx = x0b - 1 + r18;
            bool ok = ((unsigned)yy < HH) && ((unsigned)xx < WW);
            uint4 v = {0u, 0u, 0u, 0u};
            if (ok)
                v = ((const uint4*)(xt + (size_t)(b * HW + yy * WW + xx) * C2B))[c8];
            patch4[c8 * PR + run * 18 + r18] = v;
        }
    }
    __syncthreads();                        // barrier S

    // ---- Phase 1: conv partials, A from LDS, weights from registers ----
    v4f acc0 = {0.f, 0.f, 0.f, 0.f};
    v4f acc1 = {0.f, 0.f, 0.f, 0.f};
#pragma unroll
    for (int i = 0; i < 6; ++i) {
        if (i < nu) {
            int u = wid + 8 * i;            // unit = t*5+ks, wave-uniform
            int t = u / 5, ks = u - 5 * t;
            int r = (t / 3) * 18 + (t % 3) + m;
            // chunk remap (fj region permuted): {g,4+g,8+2g,9+2g,16+g}
            int c8 = (ks == 0) ? g : (ks == 1) ? 4 + g
                   : (ks == 2) ? 8 + 2 * g : (ks == 3) ? 9 + 2 * g
                   : 16 + g;
            v8s a = *(const v8s*)&patch4[c8 * PR + r];
            acc0 = __builtin_amdgcn_mfma_f32_16x16x32_bf16(a, preA[i][0], acc0, 0, 0, 0);
            acc1 = __builtin_amdgcn_mfma_f32_16x16x32_bf16(a, preA[i][1], acc1, 0, 0, 0);
        }
    }

    {                                       // publish 8 dwords/lane (scalar)
#pragma unroll
        for (int j = 0; j < 4; ++j) red1[wid][j][l] = acc0[j];
#pragma unroll
        for (int j = 0; j < 4; ++j) red1[wid][4 + j][l] = acc1[j];
    }
    __syncthreads();                        // barrier A (patch4 dead)

    {   // reduce + epilogue: wave w owns output-dword slot j = w
        int j = wid;
        float v = 0.f;
#pragma unroll
        for (int sw = 0; sw < 8; ++sw) v += red1[sw][j][l];
        int r = j & 3;
        int oc = (j < 4) ? m : 16 + m;
        int pos = g * 4 + r;
        if (oc < 18) {
            lraw[pos * 28 + oc] = v + b_off[oc];
        } else if (oc < 27) {
            lraw[pos * 28 + oc] =
                2.0f / (1.0f + __expf(-(v + b_mod[oc - 18])));
        }
    }
    __syncthreads();                        // barrier B (red1 dead, red2 born)

    // ---- Phase 2: one tap per wave (wave 7 also tap 8), weights in regs ----
    v4f acc[4];
#pragma unroll
    for (int nt = 0; nt < 4; ++nt) acc[nt] = (v4f){0.f, 0.f, 0.f, 0.f};

    const unsigned short* rowb =
        xt + (size_t)(b * HW) * C2B + 64 + g * 16;   // permuted fj base

    auto do_tap = [&](int k, const v8s (&wv)[8]) {
        int ky = k / 3, kx = k - 3 * ky;
        float dy = lraw[m * 28 + 2 * k];
        float dx = lraw[m * 28 + 2 * k + 1];
        float mm = lraw[m * 28 + 18 + k];

        float py = (float)(y - 1 + ky) + dy;
        float px = (float)(x - 1 + kx) + dx;
        float fy = floorf(py), fx = floorf(px);
        int   y0 = (int)fy,    x0 = (int)fx;
        float wy = py - fy,    wx = px - fx;
        int   y1 = y0 + 1,     x1 = x0 + 1;

        bool y0v = (y0 >= 0) && (y0 < HH);
        bool y1v = (y1 >= 0) && (y1 < HH);
        bool x0v = (x0 >= 0) && (x0 < WW);
        bool x1v = (x1 >= 0) && (x1 < WW);

        float w00 = (1.f - wy) * (1.f - wx) * ((y0v && x0v) ? mm : 0.f);
        float w01 = (1.f - wy) * wx         * ((y0v && x1v) ? mm : 0.f);
        float w10 = wy * (1.f - wx)         * ((y1v && x0v) ? mm : 0.f);
        float w11 = wy * wx                 * ((y1v && x1v) ? mm : 0.f);

        int y0c = min(max(y0, 0), HH - 1), y1c = min(max(y1, 0), HH - 1);
        int x0c = min(max(x0, 0), WW - 1), x1c = min(max(x1, 0), WW - 1);
        // permuted fj: lane's two K-chunks adjacent at +0 / +8 shorts
        const unsigned short* r00 = rowb + (size_t)(y0c * WW + x0c) * C2B;
        const unsigned short* r01 = rowb + (size_t)(y0c * WW + x1c) * C2B;
        const unsigned short* r10 = rowb + (size_t)(y1c * WW + x0c) * C2B;
        const unsigned short* r11 = rowb + (size_t)(y1c * WW + x1c) * C2B;

        // 8 gathers batched in flight; wait lands at first bil2 use
        uint4 a00 = *(const uint4*)(r00);
        uint4 a01 = *(const uint4*)(r01);
        uint4 a10 = *(const uint4*)(r10);
        uint4 a11 = *(const uint4*)(r11);
        uint4 c00 = *(const uint4*)(r00 + 8);
        uint4 c01 = *(const uint4*)(r01 + 8);
        uint4 c10 = *(const uint4*)(r10 + 8);
        uint4 c11 = *(const uint4*)(r11 + 8);

        uint4 ov0, ov1;
        ov0.x = bil2(a00.x, a01.x, a10.x, a11.x, w00, w01, w10, w11);
        ov0.y = bil2(a00.y, a01.y, a10.y, a11.y, w00, w01, w10, w11);
        ov0.z = bil2(a00.z, a01.z, a10.z, a11.z, w00, w01, w10, w11);
        ov0.w = bil2(a00.w, a01.w, a10.w, a11.w, w00, w01, w10, w11);
        ov1.x = bil2(c00.x, c01.x, c10.x, c11.x, w00, w01, w10, w11);
        ov1.y = bil2(c00.y, c01.y, c10.y, c11.y, w00, w01, w10, w11);
        ov1.z = bil2(c00.z, c01.z, c10.z, c11.z, w00, w01, w10, w11);
        ov1.w = bil2(c00.w, c01.w, c10.w, c11.w, w00, w01, w10, w11);
        v8s af0 = __builtin_bit_cast(v8s, ov0);
        v8s af1 = __builtin_bit_cast(v8s, ov1);

#pragma unroll
        for (int nt = 0; nt < 4; ++nt) {
            acc[nt] = __builtin_amdgcn_mfma_f32_16x16x32_bf16(
                af0, wv[nt * 2 + 0], acc[nt], 0, 0, 0);
            acc[nt] = __builtin_amdgcn_mfma_f32_16x16x32_bf16(
                af1, wv[nt * 2 + 1], acc[nt], 0, 0, 0);
        }
    };

    do_tap(wid, preB);
    if (wid == 7) do_tap(8, preB8);

    {                                       // publish 16 partials (scalar)
#pragma unroll
        for (int nt = 0; nt < 4; ++nt)
#pragma unroll
            for (int r = 0; r < 4; ++r)
                red2[((size_t)wid * 16 + nt * 4 + r) * 64 + l] = acc[nt][r];
    }
    __syncthreads();                        // barrier C
    {   // wave w reduces slots {nt*4+r0, nt*4+r0+1}, nt=w>>1, r0=(w&1)*2
        int nt = wid >> 1, r0 = (wid & 1) * 2;
        float v0 = 0.f, v1 = 0.f;
#pragma unroll
        for (int sw = 0; sw < 8; ++sw) {
            v0 += red2[((size_t)sw * 16 + nt * 4 + r0) * 64 + l];
            v1 += red2[((size_t)sw * 16 + nt * 4 + r0 + 1) * 64 + l];
        }
        float* op = out + ((size_t)(b * COUT + nt * 16 + m)) * HW
                  + hw0 + g * 4 + r0;
        float2 s2 = {v0, v1};
        *(float2*)op = s2;
    }
}

extern "C" void kernel_launch(void* const* d_in, const int* in_sizes, int n_in,
                              void* d_out, int out_size, void* d_ws, size_t ws_size,
                              hipStream_t stream)
{
    const float* frame_i = (const float*)d_in[0];
    const float* frame_j = (const float*)d_in[1];
    const float* flow_ij = (const float*)d_in[2];
    const float* w_off   = (const float*)d_in[3];
    const float* b_off   = (const float*)d_in[4];
    const float* w_mod   = (const float*)d_in[5];
    const float* b_mod   = (const float*)d_in[6];
    const float* w_reg   = (const float*)d_in[7];
    float* out = (float*)d_out;

    // workspace: Xt bf16 [NROW+1][192] | Wa2f | Wb2f  (~14.3 MB)
    unsigned short* xt   = (unsigned short*)d_ws;
    unsigned short* wa2f = xt + (size_t)(NROW + 1) * C2B;
    unsigned short* wb2f = wa2f + NA;

    prep_kernel<<<PXB2 + PWBLK + 1, 256, 0, stream>>>(
        frame_i, frame_j, flow_ij, w_off, w_mod, w_reg, xt, wa2f, wb2f);

    fused_kernel<<<NSTRIP, 512, 0, stream>>>(
        xt, wa2f, wb2f, b_off, b_mod, out);
}

// Round 6
// 115.531 us; speedup vs baseline: 1.1385x; 1.1385x over previous
//
#include <hip/hip_runtime.h>
#include <math.h>

#define BB   4
#define HH   96
#define WW   96
#define HW   (HH * WW)          // 9216
#define CIN  64
#define COUT 64
#define C2B  192                // bf16 row: fi[64] fj[64](permuted) flow[2] pad
                                // 384 B = 3 x 128-B lines; fj region 128-B aligned
#define NROW (BB * HW)          // 36864
#define ZROW NROW               // all-zero row
#define NSTRIP (NROW / 16)      // 2304 strips of 16 positions = fused grid
#define BPX3 (NSTRIP / 8)       // 288 fused blocks per XCD
#define NA   (9 * 5 * 2 * 512)  // wa2f elements (46080), fragment-dense
#define NW   (9 * 2 * 4 * 512)  // wb2f elements (36864), fragment-dense
#define PXB2 (NROW / 32)        // 1152 prep X-blocks (64 rows, half channels)
#define PWBLK 324               // weight blocks covering NA+NW elements
#define TSX  35                 // prep LDS tile stride (dwords), conflict-free
#define PR   55                 // patch row-dim (54 rows + 1 pad)

typedef short v8s __attribute__((ext_vector_type(8)));   // 8 bf16 = 4 VGPRs
typedef float v4f __attribute__((ext_vector_type(4)));

__device__ __forceinline__ unsigned short f2bf(float f) {
    unsigned u = __float_as_uint(f);
    return (unsigned short)((u + 0x7FFFu + ((u >> 16) & 1u)) >> 16);  // RTN-even
}
__device__ __forceinline__ unsigned pack2(float a, float b) {
    return (unsigned)f2bf(a) | ((unsigned)f2bf(b) << 16);
}
__device__ __forceinline__ unsigned bil2(unsigned a, unsigned b, unsigned c,
                                         unsigned d, float w00, float w01,
                                         float w10, float w11) {
    float lo = w00 * __uint_as_float(a << 16) + w01 * __uint_as_float(b << 16)
             + w10 * __uint_as_float(c << 16) + w11 * __uint_as_float(d << 16);
    float hi = w00 * __uint_as_float(a & 0xffff0000u)
             + w01 * __uint_as_float(b & 0xffff0000u)
             + w10 * __uint_as_float(c & 0xffff0000u)
             + w11 * __uint_as_float(d & 0xffff0000u);
    return pack2(lo, hi);
}

// ---------------------------------------------------------------------------
// Prep. R20 change: ALSO emit vt[b][plane][pos] (plane = phys fj chunk 0..7,
// 16 B per position) — a gather-optimized mirror of the fj region where
// consecutive positions are 16 B apart (in xt they are 384 B apart). Written
// from the already-staged LDS tile with coalesced 1 KB/wave stores.
// ---------------------------------------------------------------------------
__global__ __launch_bounds__(256) void prep_kernel(
    const float* __restrict__ fi, const float* __restrict__ fj,
    const float* __restrict__ fl, const float* __restrict__ w_off,
    const float* __restrict__ w_mod, const float* __restrict__ w_reg,
    unsigned short* __restrict__ xt, unsigned short* __restrict__ wa2f,
    unsigned short* __restrict__ wb2f, uint4* __restrict__ vt)
{
    int blk = blockIdx.x;
    if (blk < PXB2) {
        __shared__ __align__(16) unsigned tile[64 * TSX];  // 9 KB
        int tid = threadIdx.x;
        int p = tid & 63, cg = tid >> 6;    // position, channel-group 0..3
        int u = blk >> 1, half = blk & 1;
        int r0 = u * 64;
        int b = r0 / HW;                    // 64-row strip never straddles b
        int hwb = r0 - b * HW;              // strip base within image
        int hw = hwb + p;
        uint4* dst = (uint4*)(xt + (size_t)r0 * C2B);      // 24 quads per row
        if (half == 0) {                    // fi -> chunks 0..7
            const float* pi = fi + (size_t)b * CIN * HW + hw;
#pragma unroll
            for (int d = 0; d < 8; ++d) {
                int c = cg * 16 + 2 * d;
                tile[p * TSX + cg * 8 + d] =
                    pack2(pi[(size_t)c * HW], pi[(size_t)(c + 1) * HW]);
            }
            __syncthreads();
#pragma unroll
            for (int i = 0; i < 2; ++i) {   // 512 quads: 8 per row
                int gq = i * 256 + tid;
                int rl = gq >> 3, c4 = gq & 7;
                const unsigned* s = &tile[rl * TSX + c4 * 4];
                uint4 v = {s[0], s[1], s[2], s[3]};
                dst[rl * 24 + c4] = v;
            }
        } else {                            // fj(permuted)+flow+pad -> 8..23
            const float* pj = fj + (size_t)b * CIN * HW + hw;
#pragma unroll
            for (int d = 0; d < 8; ++d) {
                int c = cg * 16 + 2 * d;
                tile[p * TSX + cg * 8 + d] =
                    pack2(pj[(size_t)c * HW], pj[(size_t)(c + 1) * HW]);
            }
            if (cg == 0) {
                const float* pf = fl + (size_t)b * 2 * HW + hw;
                tile[p * TSX + 32] = pack2(pf[0], pf[HW]);
            }
            __syncthreads();
#pragma unroll
            for (int i = 0; i < 4; ++i) {   // 1024 quads: 16 per row (8..23)
                int gq = i * 256 + tid;
                int rl = gq >> 4, c4 = gq & 15;
                uint4 v = {0u, 0u, 0u, 0u};
                if (c4 < 8) {
                    const unsigned* s = &tile[rl * TSX + c4 * 4];
                    v.x = s[0]; v.y = s[1]; v.z = s[2]; v.w = s[3];
                } else if (c4 == 8) {
                    v.x = tile[rl * TSX + 32];
                }
                int pc4 = (c4 < 8) ? ((c4 & 3) * 2 + (c4 >> 2)) : c4;  // permute
                dst[rl * 24 + 8 + pc4] = v;
            }
            // vt mirror: plane pl (phys chunk), 64 consecutive positions.
            // orig chunk o for phys pl: o = (pl>>1) + (pl&1)*4.
#pragma unroll
            for (int i = 0; i < 2; ++i) {
                int it = i * 256 + tid;
                int pl = it >> 6, rl = it & 63;
                int o  = (pl >> 1) + (pl & 1) * 4;
                const unsigned* s = &tile[rl * TSX + o * 4];
                uint4 v = {s[0], s[1], s[2], s[3]};
                vt[((size_t)(b * 8 + pl)) * HW + hwb + rl] = v;
            }
        }
    } else if (blk < PXB2 + PWBLK) {
        int e = (blk - PXB2) * 256 + threadIdx.x;
        if (e < NA) {                       // wa2f, fragment-dense
            int t  = e / 5120;
            int r1 = e - t * 5120;
            int ks = r1 >> 10;
            int r2 = r1 & 1023;
            int nt = r2 >> 9;
            int l9 = r2 & 511;
            int l  = l9 >> 3, ee = l9 & 7;
            int m  = l & 15, g = l >> 4;
            int oc = nt * 16 + m;
            int ch = ks * 32 + g * 8 + ee;
            float v = 0.0f;
            if (oc < 27 && ch < 130) {
                if (oc < 18) v = w_off[((size_t)oc * 130 + ch) * 9 + t];
                else         v = w_mod[((size_t)(oc - 18) * 130 + ch) * 9 + t];
            }
            wa2f[e] = f2bf(v);
        } else {
            int e2 = e - NA;
            if (e2 < NW) {                  // wb2f, fragment-dense
                int k  = e2 >> 12;
                int r1 = e2 & 4095;
                int ks = r1 >> 11;
                int r2 = r1 & 2047;
                int nt = r2 >> 9;
                int l9 = r2 & 511;
                int l  = l9 >> 3, ee = l9 & 7;
                int m  = l & 15, g = l >> 4;
                int o  = nt * 16 + m;
                int c  = ks * 32 + g * 8 + ee;
                wb2f[e2] = f2bf(w_reg[((size_t)o * 64 + c) * 9 + k]);
            }
        }
    } else {
        if (threadIdx.x < 24) {             // zero row, 24 dwordx4
            uint4 z = {0u, 0u, 0u, 0u};
            ((uint4*)(xt + (size_t)ZROW * C2B))[threadIdx.x] = z;
        }
    }
}

// ---------------------------------------------------------------------------
// Fused conv + deform. R20 = R17 structure (best known: 8 waves / 16-pos
// strip, LDS-staged A, aliased LDS pools) with ONE change: phase-2 gathers
// read from vt (plane-major mirror, consecutive positions 16 B apart) instead
// of xt (positions 384 B apart). Theory: gathers were TA/L1 line-serialized
// (64 lines per wave-load); vt drops that to ~12-16 lines per load.
// ---------------------------------------------------------------------------
__global__ __launch_bounds__(512, 4) void fused_kernel(
    const unsigned short* __restrict__ xt,
    const unsigned short* __restrict__ wa2f,
    const unsigned short* __restrict__ wb2f,
    const uint4* __restrict__ vt,
    const float* __restrict__ b_off, const float* __restrict__ b_mod,
    float* __restrict__ out)
{
    // pool: [0,17600) patch4 (stage..barrier A) | [0,32768) red2 (after B)
    __shared__ __align__(16) unsigned char pool[32768];
    __shared__ __align__(16) float red1[8][8][64];    // 16 KB ph1 partials
    __shared__ float lraw[16 * 28];                   // 1.8 KB offsets/mods

    uint4* patch4 = (uint4*)pool;
    float* red2   = (float*)pool;                     // [8][16][64]

    int l = threadIdx.x & 63;
    int wid = __builtin_amdgcn_readfirstlane(threadIdx.x >> 6);  // 0..7
    int m = l & 15, g = l >> 4;
    int strip = (blockIdx.x & 7) * BPX3 + (blockIdx.x >> 3);  // XCD-contiguous
    int b = strip / (HW / 16);              // wave-uniform
    int hw0 = (strip - b * (HW / 16)) * 16;
    int hw = hw0 + m;
    int x = hw % WW, y = hw / WW;
    int y0b = hw0 / WW, x0b = hw0 - y0b * WW;   // strip base (x0b mult of 16)

    // ---- Stage the 3x18-row patch (all 9 taps' A-data), dense loads ----
#pragma unroll
    for (int i = 0; i < 3; ++i) {
        int item = i * 512 + threadIdx.x;   // (run,row18,c8) row-major
        if (item < 1080) {
            int run = item / 360;
            int rem = item - run * 360;
            int r18 = rem / 20;
            int c8  = rem - r18 * 20;
            int yy = y0b + run - 1;
            int xx = x0b - 1 + r18;
            bool ok = ((unsigned)yy < HH) && ((unsigned)xx < WW);
            uint4 v = {0u, 0u, 0u, 0u};
            if (ok)
                v = ((const uint4*)(xt + (size_t)(b * HW + yy * WW + xx) * C2B))[c8];
            patch4[c8 * PR + run * 18 + r18] = v;
        }
    }
    __syncthreads();                        // barrier S

    // ---- Phase 1: conv partials, 45 units over 8 waves (6/6/6/6/6/5/5/5) ----
    v4f acc0 = {0.f, 0.f, 0.f, 0.f};
    v4f acc1 = {0.f, 0.f, 0.f, 0.f};
    {
        int nu = (wid < 5) ? 6 : 5;         // wave-uniform unit count
#pragma unroll
        for (int i = 0; i < 6; ++i) {
            if (i < nu) {
                int u = wid + 8 * i;        // unit = t*5+ks, uniform
                int t = u / 5, ks = u - 5 * t;
                int r = (t / 3) * 18 + (t % 3) + m;
                // chunk remap (fj region permuted): {g,4+g,8+2g,9+2g,16+g}
                int c8 = (ks == 0) ? g : (ks == 1) ? 4 + g
                       : (ks == 2) ? 8 + 2 * g : (ks == 3) ? 9 + 2 * g
                       : 16 + g;
                v8s a = *(const v8s*)&patch4[c8 * PR + r];
                const unsigned short* wp =
                    wa2f + ((size_t)(u * 2)) * 512 + l * 8;
                v8s b0 = *(const v8s*)(wp);
                v8s b1 = *(const v8s*)(wp + 512);
                acc0 = __builtin_amdgcn_mfma_f32_16x16x32_bf16(a, b0, acc0, 0, 0, 0);
                acc1 = __builtin_amdgcn_mfma_f32_16x16x32_bf16(a, b1, acc1, 0, 0, 0);
            }
        }
    }

    {                                       // publish 8 dwords/lane (scalar)
#pragma unroll
        for (int j = 0; j < 4; ++j) red1[wid][j][l] = acc0[j];
#pragma unroll
        for (int j = 0; j < 4; ++j) red1[wid][4 + j][l] = acc1[j];
    }
    __syncthreads();                        // barrier A (patch4 dead)

    {   // reduce + epilogue: wave w owns output-dword slot j = w
        int j = wid;
        float v = 0.f;
#pragma unroll
        for (int sw = 0; sw < 8; ++sw) v += red1[sw][j][l];
        int r = j & 3;
        int oc = (j < 4) ? m : 16 + m;
        int pos = g * 4 + r;
        if (oc < 18) {
            lraw[pos * 28 + oc] = v + b_off[oc];
        } else if (oc < 27) {
            lraw[pos * 28 + oc] =
                2.0f / (1.0f + __expf(-(v + b_mod[oc - 18])));
        }
    }
    __syncthreads();                        // barrier B (red1 dead, red2 born)

    // ---- Phase 2: one tap per wave (wave 7 also tap 8), vt gathers ----
    v4f acc[4];
#pragma unroll
    for (int nt = 0; nt < 4; ++nt) acc[nt] = (v4f){0.f, 0.f, 0.f, 0.f};

    // lane plane bases: phys chunks 2g (ks=0) and 2g+1 (ks=1)
    const uint4* p0 = vt + ((size_t)(b * 8 + 2 * g + 0)) * HW;
    const uint4* p1 = vt + ((size_t)(b * 8 + 2 * g + 1)) * HW;

    auto do_tap = [&](int k) {
        int ky = k / 3, kx = k - 3 * ky;
        float dy = lraw[m * 28 + 2 * k];
        float dx = lraw[m * 28 + 2 * k + 1];
        float mm = lraw[m * 28 + 18 + k];

        float py = (float)(y - 1 + ky) + dy;
        float px = (float)(x - 1 + kx) + dx;
        float fy = floorf(py), fx = floorf(px);
        int   y0 = (int)fy,    x0 = (int)fx;
        float wy = py - fy,    wx = px - fx;
        int   y1 = y0 + 1,     x1 = x0 + 1;

        bool y0v = (y0 >= 0) && (y0 < HH);
        bool y1v = (y1 >= 0) && (y1 < HH);
        bool x0v = (x0 >= 0) && (x0 < WW);
        bool x1v = (x1 >= 0) && (x1 < WW);

        float w00 = (1.f - wy) * (1.f - wx) * ((y0v && x0v) ? mm : 0.f);
        float w01 = (1.f - wy) * wx         * ((y0v && x1v) ? mm : 0.f);
        float w10 = wy * (1.f - wx)         * ((y1v && x0v) ? mm : 0.f);
        float w11 = wy * wx                 * ((y1v && x1v) ? mm : 0.f);

        int y0c = min(max(y0, 0), HH - 1), y1c = min(max(y1, 0), HH - 1);
        int x0c = min(max(x0, 0), WW - 1), x1c = min(max(x1, 0), WW - 1);
        int i00 = y0c * WW + x0c, i01 = y0c * WW + x1c;
        int i10 = y1c * WW + x0c, i11 = y1c * WW + x1c;

        // 8 gathers batched in flight; consecutive lanes hit consecutive
        // 16-B slots in vt planes -> few lines per wave-load
        uint4 a00 = p0[i00];
        uint4 a01 = p0[i01];
        uint4 a10 = p0[i10];
        uint4 a11 = p0[i11];
        uint4 c00 = p1[i00];
        uint4 c01 = p1[i01];
        uint4 c10 = p1[i10];
        uint4 c11 = p1[i11];

        uint4 ov0, ov1;
        ov0.x = bil2(a00.x, a01.x, a10.x, a11.x, w00, w01, w10, w11);
        ov0.y = bil2(a00.y, a01.y, a10.y, a11.y, w00, w01, w10, w11);
        ov0.z = bil2(a00.z, a01.z, a10.z, a11.z, w00, w01, w10, w11);
        ov0.w = bil2(a00.w, a01.w, a10.w, a11.w, w00, w01, w10, w11);
        ov1.x = bil2(c00.x, c01.x, c10.x, c11.x, w00, w01, w10, w11);
        ov1.y = bil2(c00.y, c01.y, c10.y, c11.y, w00, w01, w10, w11);
        ov1.z = bil2(c00.z, c01.z, c10.z, c11.z, w00, w01, w10, w11);
        ov1.w = bil2(c00.w, c01.w, c10.w, c11.w, w00, w01, w10, w11);
        v8s af0 = __builtin_bit_cast(v8s, ov0);
        v8s af1 = __builtin_bit_cast(v8s, ov1);

#pragma unroll
        for (int nt = 0; nt < 4; ++nt) {
            const unsigned short* wp0 =
                wb2f + ((size_t)((k * 2 + 0) * 4 + nt)) * 512 + l * 8;
            const unsigned short* wp1 =
                wb2f + ((size_t)((k * 2 + 1) * 4 + nt)) * 512 + l * 8;
            v8s bb0 = *(const v8s*)wp0;
            v8s bb1 = *(const v8s*)wp1;
            acc[nt] = __builtin_amdgcn_mfma_f32_16x16x32_bf16(af0, bb0, acc[nt], 0, 0, 0);
            acc[nt] = __builtin_amdgcn_mfma_f32_16x16x32_bf16(af1, bb1, acc[nt], 0, 0, 0);
        }
    };

    do_tap(wid);
    if (wid == 7) do_tap(8);

    {                                       // publish 16 partials (scalar)
#pragma unroll
        for (int nt = 0; nt < 4; ++nt)
#pragma unroll
            for (int r = 0; r < 4; ++r)
                red2[((size_t)wid * 16 + nt * 4 + r) * 64 + l] = acc[nt][r];
    }
    __syncthreads();                        // barrier C
    {   // wave w reduces slots {nt*4+r0, nt*4+r0+1}, nt=w>>1, r0=(w&1)*2
        int nt = wid >> 1, r0 = (wid & 1) * 2;
        float v0 = 0.f, v1 = 0.f;
#pragma unroll
        for (int sw = 0; sw < 8; ++sw) {
            v0 += red2[((size_t)sw * 16 + nt * 4 + r0) * 64 + l];
            v1 += red2[((size_t)sw * 16 + nt * 4 + r0 + 1) * 64 + l];
        }
        float* op = out + ((size_t)(b * COUT + nt * 16 + m)) * HW
                  + hw0 + g * 4 + r0;
        float2 s2 = {v0, v1};
        *(float2*)op = s2;
    }
}

extern "C" void kernel_launch(void* const* d_in, const int* in_sizes, int n_in,
                              void* d_out, int out_size, void* d_ws, size_t ws_size,
                              hipStream_t stream)
{
    const float* frame_i = (const float*)d_in[0];
    const float* frame_j = (const float*)d_in[1];
    const float* flow_ij = (const float*)d_in[2];
    const float* w_off   = (const float*)d_in[3];
    const float* b_off   = (const float*)d_in[4];
    const float* w_mod   = (const float*)d_in[5];
    const float* b_mod   = (const float*)d_in[6];
    const float* w_reg   = (const float*)d_in[7];
    float* out = (float*)d_out;

    // workspace: Xt bf16 [NROW+1][192] | Wa2f | Wb2f | vt  (~19 MB)
    unsigned short* xt   = (unsigned short*)d_ws;
    unsigned short* wa2f = xt + (size_t)(NROW + 1) * C2B;
    unsigned short* wb2f = wa2f + NA;
    uint4* vt            = (uint4*)(wb2f + NW);   // 16B-aligned (all sizes /16)

    prep_kernel<<<PXB2 + PWBLK + 1, 256, 0, stream>>>(
        frame_i, frame_j, flow_ij, w_off, w_mod, w_reg, xt, wa2f, wb2f, vt);

    fused_kernel<<<NSTRIP, 512, 0, stream>>>(
        xt, wa2f, wb2f, vt, b_off, b_mod, out);
}

// Round 7
// 115.275 us; speedup vs baseline: 1.1410x; 1.0022x over previous
//
#include <hip/hip_runtime.h>
#include <math.h>

#define BB   4
#define HH   96
#define WW   96
#define HW   (HH * WW)          // 9216
#define CIN  64
#define COUT 64
#define C2B  192                // bf16 row: fi[64] fj[64](permuted) flow[2] pad
                                // 384 B = 3 x 128-B lines; fj region 128-B aligned
#define NROW (BB * HW)          // 36864
#define ZROW NROW               // all-zero row
#define NSTRIP (NROW / 16)      // 2304 strips of 16 positions = fused grid
#define BPX3 (NSTRIP / 8)       // 288 fused blocks per XCD
#define NA   (9 * 5 * 2 * 512)  // wa2f elements (46080), fragment-dense
#define NW   (9 * 2 * 4 * 512)  // wb2f elements (36864), fragment-dense
#define PXB2 (NROW / 32)        // 1152 prep X-blocks (64 rows, half channels)
#define PWBLK 324               // weight blocks covering NA+NW elements
#define TSX  35                 // prep LDS tile stride (dwords), conflict-free
#define PR   55                 // patch row-dim (54 rows + 1 pad)

typedef short v8s __attribute__((ext_vector_type(8)));   // 8 bf16 = 4 VGPRs
typedef float v4f __attribute__((ext_vector_type(4)));

__device__ __forceinline__ unsigned short f2bf(float f) {
    unsigned u = __float_as_uint(f);
    return (unsigned short)((u + 0x7FFFu + ((u >> 16) & 1u)) >> 16);  // RTN-even
}
__device__ __forceinline__ unsigned pack2(float a, float b) {
    return (unsigned)f2bf(a) | ((unsigned)f2bf(b) << 16);
}
__device__ __forceinline__ unsigned bil2(unsigned a, unsigned b, unsigned c,
                                         unsigned d, float w00, float w01,
                                         float w10, float w11) {
    float lo = w00 * __uint_as_float(a << 16) + w01 * __uint_as_float(b << 16)
             + w10 * __uint_as_float(c << 16) + w11 * __uint_as_float(d << 16);
    float hi = w00 * __uint_as_float(a & 0xffff0000u)
             + w01 * __uint_as_float(b & 0xffff0000u)
             + w10 * __uint_as_float(c & 0xffff0000u)
             + w11 * __uint_as_float(d & 0xffff0000u);
    return pack2(lo, hi);
}

// ---------------------------------------------------------------------------
// Prep (unchanged from R20/R6). Emits xt (conv layout), weight fragments, and
// vt[b][plane][pos] (plane = phys fj chunk 0..7, 16 B per position) — the
// gather-optimized mirror where consecutive positions are 16 B apart.
// ---------------------------------------------------------------------------
__global__ __launch_bounds__(256) void prep_kernel(
    const float* __restrict__ fi, const float* __restrict__ fj,
    const float* __restrict__ fl, const float* __restrict__ w_off,
    const float* __restrict__ w_mod, const float* __restrict__ w_reg,
    unsigned short* __restrict__ xt, unsigned short* __restrict__ wa2f,
    unsigned short* __restrict__ wb2f, uint4* __restrict__ vt)
{
    int blk = blockIdx.x;
    if (blk < PXB2) {
        __shared__ __align__(16) unsigned tile[64 * TSX];  // 9 KB
        int tid = threadIdx.x;
        int p = tid & 63, cg = tid >> 6;    // position, channel-group 0..3
        int u = blk >> 1, half = blk & 1;
        int r0 = u * 64;
        int b = r0 / HW;                    // 64-row strip never straddles b
        int hwb = r0 - b * HW;              // strip base within image
        int hw = hwb + p;
        uint4* dst = (uint4*)(xt + (size_t)r0 * C2B);      // 24 quads per row
        if (half == 0) {                    // fi -> chunks 0..7
            const float* pi = fi + (size_t)b * CIN * HW + hw;
#pragma unroll
            for (int d = 0; d < 8; ++d) {
                int c = cg * 16 + 2 * d;
                tile[p * TSX + cg * 8 + d] =
                    pack2(pi[(size_t)c * HW], pi[(size_t)(c + 1) * HW]);
            }
            __syncthreads();
#pragma unroll
            for (int i = 0; i < 2; ++i) {   // 512 quads: 8 per row
                int gq = i * 256 + tid;
                int rl = gq >> 3, c4 = gq & 7;
                const unsigned* s = &tile[rl * TSX + c4 * 4];
                uint4 v = {s[0], s[1], s[2], s[3]};
                dst[rl * 24 + c4] = v;
            }
        } else {                            // fj(permuted)+flow+pad -> 8..23
            const float* pj = fj + (size_t)b * CIN * HW + hw;
#pragma unroll
            for (int d = 0; d < 8; ++d) {
                int c = cg * 16 + 2 * d;
                tile[p * TSX + cg * 8 + d] =
                    pack2(pj[(size_t)c * HW], pj[(size_t)(c + 1) * HW]);
            }
            if (cg == 0) {
                const float* pf = fl + (size_t)b * 2 * HW + hw;
                tile[p * TSX + 32] = pack2(pf[0], pf[HW]);
            }
            __syncthreads();
#pragma unroll
            for (int i = 0; i < 4; ++i) {   // 1024 quads: 16 per row (8..23)
                int gq = i * 256 + tid;
                int rl = gq >> 4, c4 = gq & 15;
                uint4 v = {0u, 0u, 0u, 0u};
                if (c4 < 8) {
                    const unsigned* s = &tile[rl * TSX + c4 * 4];
                    v.x = s[0]; v.y = s[1]; v.z = s[2]; v.w = s[3];
                } else if (c4 == 8) {
                    v.x = tile[rl * TSX + 32];
                }
                int pc4 = (c4 < 8) ? ((c4 & 3) * 2 + (c4 >> 2)) : c4;  // permute
                dst[rl * 24 + 8 + pc4] = v;
            }
            // vt mirror: plane pl (phys chunk), 64 consecutive positions.
            // orig chunk o for phys pl: o = (pl>>1) + (pl&1)*4.
#pragma unroll
            for (int i = 0; i < 2; ++i) {
                int it = i * 256 + tid;
                int pl = it >> 6, rl = it & 63;
                int o  = (pl >> 1) + (pl & 1) * 4;
                const unsigned* s = &tile[rl * TSX + o * 4];
                uint4 v = {s[0], s[1], s[2], s[3]};
                vt[((size_t)(b * 8 + pl)) * HW + hwb + rl] = v;
            }
        }
    } else if (blk < PXB2 + PWBLK) {
        int e = (blk - PXB2) * 256 + threadIdx.x;
        if (e < NA) {                       // wa2f, fragment-dense
            int t  = e / 5120;
            int r1 = e - t * 5120;
            int ks = r1 >> 10;
            int r2 = r1 & 1023;
            int nt = r2 >> 9;
            int l9 = r2 & 511;
            int l  = l9 >> 3, ee = l9 & 7;
            int m  = l & 15, g = l >> 4;
            int oc = nt * 16 + m;
            int ch = ks * 32 + g * 8 + ee;
            float v = 0.0f;
            if (oc < 27 && ch < 130) {
                if (oc < 18) v = w_off[((size_t)oc * 130 + ch) * 9 + t];
                else         v = w_mod[((size_t)(oc - 18) * 130 + ch) * 9 + t];
            }
            wa2f[e] = f2bf(v);
        } else {
            int e2 = e - NA;
            if (e2 < NW) {                  // wb2f, fragment-dense
                int k  = e2 >> 12;
                int r1 = e2 & 4095;
                int ks = r1 >> 11;
                int r2 = r1 & 2047;
                int nt = r2 >> 9;
                int l9 = r2 & 511;
                int l  = l9 >> 3, ee = l9 & 7;
                int m  = l & 15, g = l >> 4;
                int o  = nt * 16 + m;
                int c  = ks * 32 + g * 8 + ee;
                wb2f[e2] = f2bf(w_reg[((size_t)o * 64 + c) * 9 + k]);
            }
        }
    } else {
        if (threadIdx.x < 24) {             // zero row, 24 dwordx4
            uint4 z = {0u, 0u, 0u, 0u};
            ((uint4*)(xt + (size_t)ZROW * C2B))[threadIdx.x] = z;
        }
    }
}

// ---------------------------------------------------------------------------
// Fused conv + deform. R21 = R20 + two structural fixes:
//  1. Phase-2 straggler split: tap 8 divided by K-half — wave 6 takes
//     (tap8,ks0), wave 7 takes (tap8,ks1). Critical path 2.0 -> 1.5 taps.
//  2. LDS diet via two-stage phase-2 reduction: red2 shrinks 8 -> 4 buffers
//     (waves 4-7 publish, waves 0-3 add-in-place, then all reduce 4 bufs).
//     red2 (16 KB) now fits inside the patch pool (17.6 KB).
//     LDS 51.2 KB -> 35.8 KB => 4 blocks/CU (32 waves, 100% static).
//  __launch_bounds__(512,8) pins VGPR<=64 (current compile already at 64).
// ---------------------------------------------------------------------------
__global__ __launch_bounds__(512, 8) void fused_kernel(
    const unsigned short* __restrict__ xt,
    const unsigned short* __restrict__ wa2f,
    const unsigned short* __restrict__ wb2f,
    const uint4* __restrict__ vt,
    const float* __restrict__ b_off, const float* __restrict__ b_mod,
    float* __restrict__ out)
{
    // pool: [0,17600) patch4 (stage..barrier A) | [0,16384) red2 (after B)
    __shared__ __align__(16) unsigned char pool[17600];
    __shared__ __align__(16) float red1[8][8][64];    // 16 KB ph1 partials
    __shared__ float lraw[16 * 28];                   // 1.8 KB offsets/mods

    uint4* patch4 = (uint4*)pool;
    float* red2   = (float*)pool;                     // [4][16][64]

    int l = threadIdx.x & 63;
    int wid = __builtin_amdgcn_readfirstlane(threadIdx.x >> 6);  // 0..7
    int m = l & 15, g = l >> 4;
    int strip = (blockIdx.x & 7) * BPX3 + (blockIdx.x >> 3);  // XCD-contiguous
    int b = strip / (HW / 16);              // wave-uniform
    int hw0 = (strip - b * (HW / 16)) * 16;
    int hw = hw0 + m;
    int x = hw % WW, y = hw / WW;
    int y0b = hw0 / WW, x0b = hw0 - y0b * WW;   // strip base (x0b mult of 16)

    // ---- Stage the 3x18-row patch (all 9 taps' A-data), dense loads ----
#pragma unroll
    for (int i = 0; i < 3; ++i) {
        int item = i * 512 + threadIdx.x;   // (run,row18,c8) row-major
        if (item < 1080) {
            int run = item / 360;
            int rem = item - run * 360;
            int r18 = rem / 20;
            int c8  = rem - r18 * 20;
            int yy = y0b + run - 1;
            int xx = x0b - 1 + r18;
            bool ok = ((unsigned)yy < HH) && ((unsigned)xx < WW);
            uint4 v = {0u, 0u, 0u, 0u};
            if (ok)
                v = ((const uint4*)(xt + (size_t)(b * HW + yy * WW + xx) * C2B))[c8];
            patch4[c8 * PR + run * 18 + r18] = v;
        }
    }
    __syncthreads();                        // barrier S

    // ---- Phase 1: conv partials, 45 units over 8 waves (6/6/6/6/6/5/5/5) ----
    v4f acc0 = {0.f, 0.f, 0.f, 0.f};
    v4f acc1 = {0.f, 0.f, 0.f, 0.f};
    {
        int nu = (wid < 5) ? 6 : 5;         // wave-uniform unit count
#pragma unroll
        for (int i = 0; i < 6; ++i) {
            if (i < nu) {
                int u = wid + 8 * i;        // unit = t*5+ks, uniform
                int t = u / 5, ks = u - 5 * t;
                int r = (t / 3) * 18 + (t % 3) + m;
                // chunk remap (fj region permuted): {g,4+g,8+2g,9+2g,16+g}
                int c8 = (ks == 0) ? g : (ks == 1) ? 4 + g
                       : (ks == 2) ? 8 + 2 * g : (ks == 3) ? 9 + 2 * g
                       : 16 + g;
                v8s a = *(const v8s*)&patch4[c8 * PR + r];
                const unsigned short* wp =
                    wa2f + ((size_t)(u * 2)) * 512 + l * 8;
                v8s b0 = *(const v8s*)(wp);
                v8s b1 = *(const v8s*)(wp + 512);
                acc0 = __builtin_amdgcn_mfma_f32_16x16x32_bf16(a, b0, acc0, 0, 0, 0);
                acc1 = __builtin_amdgcn_mfma_f32_16x16x32_bf16(a, b1, acc1, 0, 0, 0);
            }
        }
    }

    {                                       // publish 8 dwords/lane (scalar)
#pragma unroll
        for (int j = 0; j < 4; ++j) red1[wid][j][l] = acc0[j];
#pragma unroll
        for (int j = 0; j < 4; ++j) red1[wid][4 + j][l] = acc1[j];
    }
    __syncthreads();                        // barrier A (patch4 dead)

    {   // reduce + epilogue: wave w owns output-dword slot j = w
        int j = wid;
        float v = 0.f;
#pragma unroll
        for (int sw = 0; sw < 8; ++sw) v += red1[sw][j][l];
        int r = j & 3;
        int oc = (j < 4) ? m : 16 + m;
        int pos = g * 4 + r;
        if (oc < 18) {
            lraw[pos * 28 + oc] = v + b_off[oc];
        } else if (oc < 27) {
            lraw[pos * 28 + oc] =
                2.0f / (1.0f + __expf(-(v + b_mod[oc - 18])));
        }
    }
    __syncthreads();                        // barrier B (red1 dead, red2 born)

    // ---- Phase 2: wave w owns tap w; tap 8 split by ks to waves 6/7 ----
    v4f acc[4];
#pragma unroll
    for (int nt = 0; nt < 4; ++nt) acc[nt] = (v4f){0.f, 0.f, 0.f, 0.f};

    // full tap: 8 batched gathers (both planes), preserves R6 codegen
    auto do_tap = [&](int k) {
        int ky = k / 3, kx = k - 3 * ky;
        float dy = lraw[m * 28 + 2 * k];
        float dx = lraw[m * 28 + 2 * k + 1];
        float mm = lraw[m * 28 + 18 + k];

        float py = (float)(y - 1 + ky) + dy;
        float px = (float)(x - 1 + kx) + dx;
        float fy = floorf(py), fx = floorf(px);
        int   y0 = (int)fy,    x0 = (int)fx;
        float wy = py - fy,    wx = px - fx;
        int   y1 = y0 + 1,     x1 = x0 + 1;

        bool y0v = (y0 >= 0) && (y0 < HH);
        bool y1v = (y1 >= 0) && (y1 < HH);
        bool x0v = (x0 >= 0) && (x0 < WW);
        bool x1v = (x1 >= 0) && (x1 < WW);

        float w00 = (1.f - wy) * (1.f - wx) * ((y0v && x0v) ? mm : 0.f);
        float w01 = (1.f - wy) * wx         * ((y0v && x1v) ? mm : 0.f);
        float w10 = wy * (1.f - wx)         * ((y1v && x0v) ? mm : 0.f);
        float w11 = wy * wx                 * ((y1v && x1v) ? mm : 0.f);

        int y0c = min(max(y0, 0), HH - 1), y1c = min(max(y1, 0), HH - 1);
        int x0c = min(max(x0, 0), WW - 1), x1c = min(max(x1, 0), WW - 1);
        int i00 = y0c * WW + x0c, i01 = y0c * WW + x1c;
        int i10 = y1c * WW + x0c, i11 = y1c * WW + x1c;

        const uint4* p0 = vt + ((size_t)(b * 8 + 2 * g + 0)) * HW;
        const uint4* p1 = vt + ((size_t)(b * 8 + 2 * g + 1)) * HW;

        uint4 a00 = p0[i00];
        uint4 a01 = p0[i01];
        uint4 a10 = p0[i10];
        uint4 a11 = p0[i11];
        uint4 c00 = p1[i00];
        uint4 c01 = p1[i01];
        uint4 c10 = p1[i10];
        uint4 c11 = p1[i11];

        uint4 ov0, ov1;
        ov0.x = bil2(a00.x, a01.x, a10.x, a11.x, w00, w01, w10, w11);
        ov0.y = bil2(a00.y, a01.y, a10.y, a11.y, w00, w01, w10, w11);
        ov0.z = bil2(a00.z, a01.z, a10.z, a11.z, w00, w01, w10, w11);
        ov0.w = bil2(a00.w, a01.w, a10.w, a11.w, w00, w01, w10, w11);
        ov1.x = bil2(c00.x, c01.x, c10.x, c11.x, w00, w01, w10, w11);
        ov1.y = bil2(c00.y, c01.y, c10.y, c11.y, w00, w01, w10, w11);
        ov1.z = bil2(c00.z, c01.z, c10.z, c11.z, w00, w01, w10, w11);
        ov1.w = bil2(c00.w, c01.w, c10.w, c11.w, w00, w01, w10, w11);
        v8s af0 = __builtin_bit_cast(v8s, ov0);
        v8s af1 = __builtin_bit_cast(v8s, ov1);

#pragma unroll
        for (int nt = 0; nt < 4; ++nt) {
            const unsigned short* wp0 =
                wb2f + ((size_t)((k * 2 + 0) * 4 + nt)) * 512 + l * 8;
            const unsigned short* wp1 =
                wb2f + ((size_t)((k * 2 + 1) * 4 + nt)) * 512 + l * 8;
            v8s bb0 = *(const v8s*)wp0;
            v8s bb1 = *(const v8s*)wp1;
            acc[nt] = __builtin_amdgcn_mfma_f32_16x16x32_bf16(af0, bb0, acc[nt], 0, 0, 0);
            acc[nt] = __builtin_amdgcn_mfma_f32_16x16x32_bf16(af1, bb1, acc[nt], 0, 0, 0);
        }
    };

    // half tap: one K-half (plane ks), 4 gathers + 4 MFMA
    auto do_half = [&](int k, int ks) {
        int ky = k / 3, kx = k - 3 * ky;
        float dy = lraw[m * 28 + 2 * k];
        float dx = lraw[m * 28 + 2 * k + 1];
        float mm = lraw[m * 28 + 18 + k];

        float py = (float)(y - 1 + ky) + dy;
        float px = (float)(x - 1 + kx) + dx;
        float fy = floorf(py), fx = floorf(px);
        int   y0 = (int)fy,    x0 = (int)fx;
        float wy = py - fy,    wx = px - fx;
        int   y1 = y0 + 1,     x1 = x0 + 1;

        bool y0v = (y0 >= 0) && (y0 < HH);
        bool y1v = (y1 >= 0) && (y1 < HH);
        bool x0v = (x0 >= 0) && (x0 < WW);
        bool x1v = (x1 >= 0) && (x1 < WW);

        float w00 = (1.f - wy) * (1.f - wx) * ((y0v && x0v) ? mm : 0.f);
        float w01 = (1.f - wy) * wx         * ((y0v && x1v) ? mm : 0.f);
        float w10 = wy * (1.f - wx)         * ((y1v && x0v) ? mm : 0.f);
        float w11 = wy * wx                 * ((y1v && x1v) ? mm : 0.f);

        int y0c = min(max(y0, 0), HH - 1), y1c = min(max(y1, 0), HH - 1);
        int x0c = min(max(x0, 0), WW - 1), x1c = min(max(x1, 0), WW - 1);
        int i00 = y0c * WW + x0c, i01 = y0c * WW + x1c;
        int i10 = y1c * WW + x0c, i11 = y1c * WW + x1c;

        const uint4* pk = vt + ((size_t)(b * 8 + 2 * g + ks)) * HW;
        uint4 a00 = pk[i00];
        uint4 a01 = pk[i01];
        uint4 a10 = pk[i10];
        uint4 a11 = pk[i11];

        uint4 ov;
        ov.x = bil2(a00.x, a01.x, a10.x, a11.x, w00, w01, w10, w11);
        ov.y = bil2(a00.y, a01.y, a10.y, a11.y, w00, w01, w10, w11);
        ov.z = bil2(a00.z, a01.z, a10.z, a11.z, w00, w01, w10, w11);
        ov.w = bil2(a00.w, a01.w, a10.w, a11.w, w00, w01, w10, w11);
        v8s af = __builtin_bit_cast(v8s, ov);

#pragma unroll
        for (int nt = 0; nt < 4; ++nt) {
            const unsigned short* wp =
                wb2f + ((size_t)((k * 2 + ks) * 4 + nt)) * 512 + l * 8;
            v8s bb = *(const v8s*)wp;
            acc[nt] = __builtin_amdgcn_mfma_f32_16x16x32_bf16(af, bb, acc[nt], 0, 0, 0);
        }
    };

    do_tap(wid);
    if (wid == 6) do_half(8, 0);
    if (wid == 7) do_half(8, 1);

    // ---- Two-stage cross-wave reduction (red2 = 4 buffers, 16 KB) ----
    if (wid >= 4) {                         // stage A: waves 4-7 publish
        float* rb = red2 + ((size_t)(wid - 4) * 16) * 64;
#pragma unroll
        for (int nt = 0; nt < 4; ++nt)
#pragma unroll
            for (int r = 0; r < 4; ++r)
                rb[(nt * 4 + r) * 64 + l] = acc[nt][r];
    }
    __syncthreads();                        // barrier C1
    if (wid < 4) {                          // stage B: waves 0-3 add in place
        float* rb = red2 + ((size_t)wid * 16) * 64;
#pragma unroll
        for (int nt = 0; nt < 4; ++nt)
#pragma unroll
            for (int r = 0; r < 4; ++r) {
                float t = rb[(nt * 4 + r) * 64 + l] + acc[nt][r];
                rb[(nt * 4 + r) * 64 + l] = t;
            }
    }
    __syncthreads();                        // barrier C2
    {   // stage C: wave w reduces slots {nt*4+r0, +1} over 4 buffers
        int nt = wid >> 1, r0 = (wid & 1) * 2;
        float v0 = 0.f, v1 = 0.f;
#pragma unroll
        for (int bu = 0; bu < 4; ++bu) {
            v0 += red2[((size_t)bu * 16 + nt * 4 + r0) * 64 + l];
            v1 += red2[((size_t)bu * 16 + nt * 4 + r0 + 1) * 64 + l];
        }
        float* op = out + ((size_t)(b * COUT + nt * 16 + m)) * HW
                  + hw0 + g * 4 + r0;
        float2 s2 = {v0, v1};
        *(float2*)op = s2;
    }
}

extern "C" void kernel_launch(void* const* d_in, const int* in_sizes, int n_in,
                              void* d_out, int out_size, void* d_ws, size_t ws_size,
                              hipStream_t stream)
{
    const float* frame_i = (const float*)d_in[0];
    const float* frame_j = (const float*)d_in[1];
    const float* flow_ij = (const float*)d_in[2];
    const float* w_off   = (const float*)d_in[3];
    const float* b_off   = (const float*)d_in[4];
    const float* w_mod   = (const float*)d_in[5];
    const float* b_mod   = (const float*)d_in[6];
    const float* w_reg   = (const float*)d_in[7];
    float* out = (float*)d_out;

    // workspace: Xt bf16 [NROW+1][192] | Wa2f | Wb2f | vt  (~19 MB)
    unsigned short* xt   = (unsigned short*)d_ws;
    unsigned short* wa2f = xt + (size_t)(NROW + 1) * C2B;
    unsigned short* wb2f = wa2f + NA;
    uint4* vt            = (uint4*)(wb2f + NW);   // 16B-aligned (all sizes /16)

    prep_kernel<<<PXB2 + PWBLK + 1, 256, 0, stream>>>(
        frame_i, frame_j, flow_ij, w_off, w_mod, w_reg, xt, wa2f, wb2f, vt);

    fused_kernel<<<NSTRIP, 512, 0, stream>>>(
        xt, wa2f, wb2f, vt, b_off, b_mod, out);
}